// Round 14
// baseline (352.267 us; speedup 1.0000x reference)
//
#include <hip/hip_runtime.h>
#include <hip/hip_bf16.h>

#define NSAMP 131072
#define TA    90
#define HID   128
#define DLAT  512

// d_out layout (float elements): quant[N*512], code[N*4], recon[N*90], loss[1]
#define OFF_CODE  67108864ll
#define OFF_RECON (67108864ll + 524288ll)
#define OFF_LOSS  (67108864ll + 524288ll + 11796480ll)

// k_encvq LDS (floats): arena[8704] | PZ[4][64]=256  -> 35 KB, 4 blocks/CU
// arena: X splits (ushort hi 0..4095, lo 4096..8191) -> h1 splits (same slots)
// -> h2 splits (same slots) -> zdot[64][129] (0..8255) | mask 8256 |
// H2A 8272..8399 | H2B 8400..8527
#define PZF    8704
#define SHF    8960
#define MSKF   8256
#define H2AF   8272
#define H2BF   8400
#define TAU    0.08f

typedef __attribute__((ext_vector_type(8))) short bf16x8;
typedef __attribute__((ext_vector_type(4))) short s16x4;
typedef __attribute__((ext_vector_type(4))) float f32x4;
typedef unsigned short ushort_t;
#define MFMA16(a, b, c) __builtin_amdgcn_mfma_f32_16x16x32_bf16(a, b, c, 0, 0, 0)

__device__ __forceinline__ ushort_t f2bf(float f) {
    unsigned u = __float_as_uint(f);
    u = (u + 0x7FFF + ((u >> 16) & 1)) >> 16;     // RNE
    return (ushort_t)u;
}
__device__ __forceinline__ float bf2f(ushort_t u) {
    return __uint_as_float(((unsigned)u) << 16);
}

__device__ __forceinline__ float dot512(const float* __restrict__ a,
                                        const float* __restrict__ b) {
    float s = 0.f;
    for (int i = 0; i < 128; ++i) {
        float4 x = ((const float4*)a)[i], y = ((const float4*)b)[i];
        s += x.x * y.x + x.y * y.y + x.z * y.z + x.w * y.w;
    }
    return s;
}

// ---------------------------------------------------------------------------
// K0: precompute tables. tbl6: Mhi/Mlo; tbl7: w2e splits; tbl8: w1e splits.
// ---------------------------------------------------------------------------
__global__ void k_prep(const float* __restrict__ cb, const float* __restrict__ w3,
                       const float* __restrict__ b3, const float* __restrict__ w1d,
                       const float* __restrict__ w2d, const float* __restrict__ w3d,
                       const float* __restrict__ w2e, const float* __restrict__ w1e,
                       float* __restrict__ P, float* __restrict__ M,
                       float* __restrict__ t0, float* __restrict__ v,
                       float* __restrict__ csc, float* __restrict__ cbW,
                       ushort_t* __restrict__ Qbf, ushort_t* __restrict__ w2bf,
                       ushort_t* __restrict__ w3bf,
                       ushort_t* __restrict__ Mhibf, ushort_t* __restrict__ Mlobf,
                       ushort_t* __restrict__ w2ehi, ushort_t* __restrict__ w2elo,
                       ushort_t* __restrict__ w1ehi, ushort_t* __restrict__ w1elo) {
    int tbl = blockIdx.x >> 6;
    int gid = (blockIdx.x & 63) * 256 + threadIdx.x;   // 0..16383
    int i = gid >> 7, j = gid & 127;
    if (tbl == 0) {
        P[gid] = dot512(cb + (size_t)i * 512, cb + (size_t)j * 512);
        if (gid < 128) t0[gid] = dot512(cb + (size_t)gid * 512, b3);
        if (gid == 0) csc[0] = dot512(b3, b3);
    } else if (tbl == 1) {
        M[gid] = dot512(w3 + (size_t)i * 512, cb + (size_t)j * 512);
    } else if (tbl == 2) {
        Qbf[gid] = f2bf(dot512(w3 + (size_t)i * 512, w3 + (size_t)j * 512));
        if (gid < 128) v[gid] = dot512(w3 + (size_t)gid * 512, b3);
    } else if (tbl == 3) {
        float s = 0.f;
        for (int d = 0; d < 512; ++d) s = fmaf(cb[(size_t)i * 512 + d], w1d[d * 128 + j], s);
        cbW[gid] = s;
    } else if (tbl == 4) {
        w2bf[gid] = f2bf(w2d[j * 128 + i]);            // [o][j] = w2d[j][o]
    } else if (tbl == 5) {
        if (gid < 96 * 128)
            w3bf[gid] = (i < 90) ? f2bf(w3d[j * TA + i]) : (ushort_t)0;
    } else if (tbl == 6) {
        float d = dot512(w3 + (size_t)j * 512, cb + (size_t)i * 512);
        ushort_t hi = f2bf(d);
        Mhibf[gid] = hi;
        Mlobf[gid] = f2bf(d - bf2f(hi));
    } else if (tbl == 7) {
        float d = w2e[j * 128 + i];
        ushort_t hi = f2bf(d);
        w2ehi[gid] = hi;
        w2elo[gid] = f2bf(d - bf2f(hi));
    } else {
        // tbl8: i = out o, j = input j. enc_w1^T split; j>=90 MUST be zero.
        float d = (j < 90) ? w1e[(size_t)j * 128 + i] : 0.f;
        ushort_t hi = f2bf(d);
        w1ehi[gid] = hi;
        w1elo[gid] = f2bf(d - bf2f(hi));
    }
}

// ---------------------------------------------------------------------------
// K1: all-MFMA encoder (L1, L2, scoring, Q all split-bf16) + argmin with
// pair-parallel exact full-chain fallback (h1 recomputed from global X).
// LDS 35 KB -> 4 blocks/CU.
// ---------------------------------------------------------------------------
__launch_bounds__(256, 4)
__global__ void k_encvq(const float* __restrict__ X,
                        const float* __restrict__ w1, const float* __restrict__ b1,
                        const float* __restrict__ w2, const float* __restrict__ b2,
                        const ushort_t* __restrict__ w1ehi, const ushort_t* __restrict__ w1elo,
                        const ushort_t* __restrict__ w2ehi, const ushort_t* __restrict__ w2elo,
                        const float* __restrict__ Mt, const ushort_t* __restrict__ Qbf,
                        const ushort_t* __restrict__ Mhi, const ushort_t* __restrict__ Mlo,
                        const float* __restrict__ t0g, const float* __restrict__ vg,
                        const float* __restrict__ cg, const float* __restrict__ Pg,
                        float* __restrict__ codes_out, float* __restrict__ loss_acc) {
    __shared__ __align__(16) float SH[SHF];
    ushort_t* sphi = (ushort_t*)SH;            // X -> h1 -> h2 hi: floats 0..4095
    ushort_t* splo = (ushort_t*)(SH + 4096);   // lo splits: floats 4096..8191
    const int t = threadIdx.x;
    const int row0 = blockIdx.x * 64;
    const int wv = t >> 6, lane = t & 63, lr = lane & 15, lg = lane >> 4;

    // ---- stage X as bf16 hi/lo splits, swizzled [s][j<96] (j>=90 zero)
    for (int it = 0; it < 24; ++it) {
        int idx = it * 256 + t;                // 0..6143 = 64 samples x 96
        int s = idx / 96, j = idx - 96 * s;
        float xv = (j < 90) ? X[(size_t)(row0 + s) * TA + j] : 0.f;
        ushort_t hi = f2bf(xv);
        int adr = ((s << 7) + j) ^ ((s & 7) << 3);
        sphi[adr] = hi;
        splo[adr] = f2bf(xv - bf2f(hi));
    }
    __syncthreads();

    // ---- L1 via split-bf16 MFMA: h1 = relu(w1e·x + b1), 3-term, K=96
    {
        f32x4 c1[2][4];
#pragma unroll
        for (int m = 0; m < 2; ++m)
#pragma unroll
            for (int n = 0; n < 4; ++n) c1[m][n] = (f32x4){0.f, 0.f, 0.f, 0.f};
#pragma unroll
        for (int kt = 0; kt < 3; ++kt) {
            bf16x8 ah[2], al[2], bhi[4], blo[4];
#pragma unroll
            for (int m = 0; m < 2; ++m) {
                int arow = (32 * wv + 16 * m + lr) * 128 + kt * 32 + lg * 8;
                ah[m] = *(const bf16x8*)&w1ehi[arow];
                al[m] = *(const bf16x8*)&w1elo[arow];
            }
#pragma unroll
            for (int n = 0; n < 4; ++n) {
                int s = 16 * n + lr;
                int adr = ((s << 7) + kt * 32 + lg * 8) ^ ((s & 7) << 3);
                bhi[n] = *(const bf16x8*)&sphi[adr];
                blo[n] = *(const bf16x8*)&splo[adr];
            }
#pragma unroll
            for (int m = 0; m < 2; ++m)
#pragma unroll
                for (int n = 0; n < 4; ++n) {
                    c1[m][n] = MFMA16(ah[m], bhi[n], c1[m][n]);
                    c1[m][n] = MFMA16(ah[m], blo[n], c1[m][n]);
                    c1[m][n] = MFMA16(al[m], bhi[n], c1[m][n]);
                }
        }
        __syncthreads();   // all X reads done -> slots reusable for h1
        float rbf[2][4];
#pragma unroll
        for (int m = 0; m < 2; ++m)
#pragma unroll
            for (int r = 0; r < 4; ++r) rbf[m][r] = b1[32 * wv + 16 * m + lg * 4 + r];
#pragma unroll
        for (int m = 0; m < 2; ++m)
#pragma unroll
            for (int n = 0; n < 4; ++n) {
                int s = 16 * n + lr;
                s16x4 ph, pl;
#pragma unroll
                for (int r = 0; r < 4; ++r) {
                    float hv = fmaxf(c1[m][n][r] + rbf[m][r], 0.f);
                    ushort_t hi = f2bf(hv);
                    ph[r] = (short)hi;
                    pl[r] = (short)f2bf(hv - bf2f(hi));
                }
                int ob2 = 32 * wv + 16 * m + lg * 4;
                int adr = ((s << 7) + ob2) ^ ((s & 7) << 3);
                *(s16x4*)&sphi[adr] = ph;
                *(s16x4*)&splo[adr] = pl;
            }
    }
    __syncthreads();

    // ---- L2 via split-bf16 MFMA: h2 = relu(w2e·h1 + b2), 3-term (R13 verbatim)
    {
        f32x4 c2[2][4];
#pragma unroll
        for (int m = 0; m < 2; ++m)
#pragma unroll
            for (int n = 0; n < 4; ++n) c2[m][n] = (f32x4){0.f, 0.f, 0.f, 0.f};
#pragma unroll
        for (int kt = 0; kt < 4; ++kt) {
            bf16x8 ah[2], al[2], bhi[4], blo[4];
#pragma unroll
            for (int m = 0; m < 2; ++m) {
                int arow = (32 * wv + 16 * m + lr) * 128 + kt * 32 + lg * 8;
                ah[m] = *(const bf16x8*)&w2ehi[arow];
                al[m] = *(const bf16x8*)&w2elo[arow];
            }
#pragma unroll
            for (int n = 0; n < 4; ++n) {
                int s = 16 * n + lr;
                int adr = ((s << 7) + kt * 32 + lg * 8) ^ ((s & 7) << 3);
                bhi[n] = *(const bf16x8*)&sphi[adr];
                blo[n] = *(const bf16x8*)&splo[adr];
            }
#pragma unroll
            for (int m = 0; m < 2; ++m)
#pragma unroll
                for (int n = 0; n < 4; ++n) {
                    c2[m][n] = MFMA16(ah[m], bhi[n], c2[m][n]);
                    c2[m][n] = MFMA16(ah[m], blo[n], c2[m][n]);
                    c2[m][n] = MFMA16(al[m], bhi[n], c2[m][n]);
                }
        }
        __syncthreads();   // all h1-split reads done -> slots reusable for h2
        float rbf[2][4];
#pragma unroll
        for (int m = 0; m < 2; ++m)
#pragma unroll
            for (int r = 0; r < 4; ++r) rbf[m][r] = b2[32 * wv + 16 * m + lg * 4 + r];
#pragma unroll
        for (int m = 0; m < 2; ++m)
#pragma unroll
            for (int n = 0; n < 4; ++n) {
                int s = 16 * n + lr;
                s16x4 ph, pl;
#pragma unroll
                for (int r = 0; r < 4; ++r) {
                    float hv = fmaxf(c2[m][n][r] + rbf[m][r], 0.f);
                    ushort_t hi = f2bf(hv);
                    ph[r] = (short)hi;
                    pl[r] = (short)f2bf(hv - bf2f(hi));
                }
                int ob2 = 32 * wv + 16 * m + lg * 4;
                int adr = ((s << 7) + ob2) ^ ((s & 7) << 3);
                *(s16x4*)&sphi[adr] = ph;
                *(s16x4*)&splo[adr] = pl;
            }
    }
    __syncthreads();

    // ---- MFMA phase: qc = Q*h2hi; sc = Mhi*hi + Mhi*lo + Mlo*hi (R13 verbatim)
    f32x4 sc[2][4];
    {
        f32x4 qc[2][4];
#pragma unroll
        for (int m = 0; m < 2; ++m)
#pragma unroll
            for (int n = 0; n < 4; ++n) {
                qc[m][n] = (f32x4){0.f, 0.f, 0.f, 0.f};
                sc[m][n] = (f32x4){0.f, 0.f, 0.f, 0.f};
            }
#pragma unroll
        for (int kt = 0; kt < 4; ++kt) {
            bf16x8 aq[2], amh[2], aml[2], bhi[4], blo[4];
#pragma unroll
            for (int m = 0; m < 2; ++m) {
                int arow = (32 * wv + 16 * m + lr) * 128 + kt * 32 + lg * 8;
                aq[m]  = *(const bf16x8*)&Qbf[arow];
                amh[m] = *(const bf16x8*)&Mhi[arow];
                aml[m] = *(const bf16x8*)&Mlo[arow];
            }
#pragma unroll
            for (int n = 0; n < 4; ++n) {
                int s = 16 * n + lr;
                int adr = ((s << 7) + kt * 32 + lg * 8) ^ ((s & 7) << 3);
                bhi[n] = *(const bf16x8*)&sphi[adr];
                blo[n] = *(const bf16x8*)&splo[adr];
            }
#pragma unroll
            for (int m = 0; m < 2; ++m)
#pragma unroll
                for (int n = 0; n < 4; ++n) {
                    qc[m][n] = MFMA16(aq[m], bhi[n], qc[m][n]);
                    sc[m][n] = MFMA16(amh[m], bhi[n], sc[m][n]);
                    sc[m][n] = MFMA16(amh[m], blo[n], sc[m][n]);
                    sc[m][n] = MFMA16(aml[m], bhi[n], sc[m][n]);
                }
        }
        float v2[2][4];
#pragma unroll
        for (int m = 0; m < 2; ++m)
#pragma unroll
            for (int r = 0; r < 4; ++r) v2[m][r] = 2.f * vg[32 * wv + 16 * m + lg * 4 + r];
#pragma unroll
        for (int n = 0; n < 4; ++n) {
            int s = 16 * n + lr;
            float p = 0.f;
#pragma unroll
            for (int m = 0; m < 2; ++m)
#pragma unroll
                for (int r = 0; r < 4; ++r) {
                    int o = 32 * wv + 16 * m + lg * 4 + r;
                    int adr = ((s << 7) + o) ^ ((s & 7) << 3);
                    float hv = bf2f(sphi[adr]) + bf2f(splo[adr]);
                    p = fmaf(qc[m][n][r] + v2[m][r], hv, p);
                }
            p += __shfl_xor(p, 16);
            p += __shfl_xor(p, 32);
            if (lg == 0) SH[PZF + wv * 64 + s] = p;
        }
    }
    __syncthreads();   // all h2 reads done -> arena reusable for zdot

    // dump S (+t0) as zdot, stride 129
#pragma unroll
    for (int m = 0; m < 2; ++m)
#pragma unroll
        for (int n = 0; n < 4; ++n) {
            int s = 16 * n + lr;
#pragma unroll
            for (int r = 0; r < 4; ++r) {
                int o = 32 * wv + 16 * m + lg * 4 + r;
                SH[s * 129 + o] = sc[m][n][r] + t0g[o];
            }
        }
    __syncthreads();

    // ---- fast argmin chain with margin tracking; wave-0 ballot -> mask
    int cs[4];
    if (t < 64) {
        float marg = 3.4e38f;
#pragma unroll
        for (int g = 0; g < 4; ++g) {
            float best = 3.4e38f, best2 = 3.4e38f; int bi = g * 32;
#pragma unroll
            for (int k = 0; k < 32; ++k) {
                int c = g * 32 + k;
                float zd = SH[t * 129 + c];
                float nr = Pg[c * 128 + c];
                float a2 = 0.f;
#pragma unroll
                for (int gp = 0; gp < g; ++gp) a2 += Pg[cs[gp] * 128 + c];
                float dist = nr - 2.f * (zd - a2);
                if (dist < best) { best2 = best; best = dist; bi = c; }
                else if (dist < best2) { best2 = dist; }
            }
            cs[g] = bi;
            float m2 = best2 - best;
            marg = (m2 < marg) ? m2 : marg;
        }
        unsigned long long mk = __ballot(marg < TAU);
        if (t == 0) *(unsigned long long*)&SH[MSKF] = mk;
    }
    __syncthreads();

    const unsigned long long mask = *(const unsigned long long*)&SH[MSKF];

    // ---- exact full-chain fallback, two samples at a time.
    // h1 from global X (ascending-j fmaf == R9 chain incl. zero-pad no-ops);
    // h2, zdot identical chains.
    {
        unsigned long long mk = mask;
        while (mk) {
            int nA = (int)__ffsll((long long)mk) - 1; mk &= mk - 1;
            int nB = -1;
            if (mk) { nB = (int)__ffsll((long long)mk) - 1; mk &= mk - 1; }
            int grp = t >> 7, tt = t & 127;
            int s2 = grp ? nB : nA;
            float hv1 = 0.f;
            if (s2 >= 0) {
                const float* xr = X + (size_t)(row0 + s2) * TA;
                for (int j = 0; j < 90; ++j)
                    hv1 = fmaf(xr[j], w1[j * 128 + tt], hv1);
                hv1 = fmaxf(hv1 + b1[tt], 0.f);
                SH[(grp ? H2BF : H2AF) + tt] = hv1;
            }
            __syncthreads();
            float hv2 = 0.f;
            if (s2 >= 0) {
                const float* h1c = &SH[grp ? H2BF : H2AF];
                for (int j = 0; j < 128; ++j)
                    hv2 = fmaf(h1c[j], w2[(size_t)j * 128 + tt], hv2);
                hv2 = fmaxf(hv2 + b2[tt], 0.f);
            }
            __syncthreads();   // all h1 reads done
            if (s2 >= 0) SH[(grp ? H2BF : H2AF) + tt] = hv2;
            __syncthreads();
            if (s2 >= 0) {
                const float* h2c = &SH[grp ? H2BF : H2AF];
                float a = 0.f;
                for (int j = 0; j < 128; ++j)
                    a = fmaf(h2c[j], Mt[(size_t)j * 128 + tt], a);
                SH[s2 * 129 + tt] = a + t0g[tt];
            }
            __syncthreads();
        }
    }

    // ---- redo argmin for flagged lanes on exact zdot
    if (t < 64 && ((mask >> t) & 1ull)) {
#pragma unroll
        for (int g = 0; g < 4; ++g) {
            float best = 3.4e38f; int bi = g * 32;
#pragma unroll
            for (int k = 0; k < 32; ++k) {
                int c = g * 32 + k;
                float zd = SH[t * 129 + c];
                float nr = Pg[c * 128 + c];
                float a2 = 0.f;
#pragma unroll
                for (int gp = 0; gp < g; ++gp) a2 += Pg[cs[gp] * 128 + c];
                float dist = nr - 2.f * (zd - a2);
                if (dist < best) { best = dist; bi = c; }
            }
            cs[g] = bi;
        }
    }

    // ---- loss + codes from final choices
    if (t < 64) {
        float znorm = cg[0] + SH[PZF + t] + SH[PZF + 64 + t]
                    + SH[PZF + 128 + t] + SH[PZF + 192 + t];
        float S1 = 0.f, Sp = 0.f, msum = 0.f;
#pragma unroll
        for (int g = 0; g < 4; ++g) {
            int c = cs[g];
            float zd = SH[t * 129 + c];
            float nr = Pg[c * 128 + c];
            float a2 = 0.f;
#pragma unroll
            for (int gp = 0; gp < g; ++gp) a2 += Pg[cs[gp] * 128 + c];
            S1 += zd;
            Sp += nr + 2.f * a2;
            msum += (znorm - 2.f * S1 + Sp);
            codes_out[(size_t)(row0 + t) * 4 + g] = (float)(c - g * 32);
        }
#pragma unroll
        for (int off = 32; off; off >>= 1) msum += __shfl_down(msum, off);
        if (t == 0) atomicAdd(&loss_acc[0], msum);
    }
}

// ---------------------------------------------------------------------------
// K2: quant write (fp32) + cbW-gather L1 (fp32) + bf16-MFMA decoder L2/L3.
// (R9 verbatim)
// ---------------------------------------------------------------------------
__launch_bounds__(256, 4)
__global__ void k_dec(const float* __restrict__ codes_f, const float* __restrict__ cb,
                      const float* __restrict__ cbW, const float* __restrict__ b1,
                      const ushort_t* __restrict__ w2bf, const float* __restrict__ b2,
                      const ushort_t* __restrict__ w3bf, const float* __restrict__ b3,
                      float* __restrict__ quant_out, float* __restrict__ recon_out) {
    __shared__ __align__(16) unsigned char SHB[39424];
    int* cods = (int*)SHB;
    ushort_t* h2bf = (ushort_t*)SHB;
    ushort_t* h1bf = (ushort_t*)(SHB + 16384);
    float* Rl = (float*)(SHB + 16384);
    const int t = threadIdx.x;
    const int st = t & 15, ct = t >> 4;
    const int s0 = st * 4, o0 = ct * 8;
    const int row0 = blockIdx.x * 64;

    cods[t] = ((t & 3) << 5) + (int)codes_f[(size_t)row0 * 4 + t];
    float rb1[8];
#pragma unroll
    for (int i = 0; i < 8; ++i) rb1[i] = b1[o0 + i];
    __syncthreads();

    for (int i = 0; i < 32; ++i) {
        int idx4 = i * 256 + t;
        int s = idx4 >> 7, d4 = (idx4 & 127) * 4;
        const int* cp = &cods[s * 4];
        float4 a = *(const float4*)&cb[(size_t)cp[0] * 512 + d4];
        float4 b = *(const float4*)&cb[(size_t)cp[1] * 512 + d4];
        float4 c = *(const float4*)&cb[(size_t)cp[2] * 512 + d4];
        float4 d = *(const float4*)&cb[(size_t)cp[3] * 512 + d4];
        float4 vv;
        vv.x = a.x + b.x + c.x + d.x;
        vv.y = a.y + b.y + c.y + d.y;
        vv.z = a.z + b.z + c.z + d.z;
        vv.w = a.w + b.w + c.w + d.w;
        *(float4*)&quant_out[(size_t)(row0 + s) * 512 + d4] = vv;
    }

    {
        float accL[8][4];
#pragma unroll
        for (int b = 0; b < 4; ++b) {
            const int* cp = &cods[(s0 + b) * 4];
            float u[8] = {0, 0, 0, 0, 0, 0, 0, 0};
#pragma unroll
            for (int g = 0; g < 4; ++g) {
                const float* r = &cbW[(size_t)cp[g] * 128 + o0];
                float4 x0 = *(const float4*)r, x1 = *(const float4*)(r + 4);
                u[0] += x0.x; u[1] += x0.y; u[2] += x0.z; u[3] += x0.w;
                u[4] += x1.x; u[5] += x1.y; u[6] += x1.z; u[7] += x1.w;
            }
#pragma unroll
            for (int a = 0; a < 8; ++a) accL[a][b] = u[a];
        }
#pragma unroll
        for (int b = 0; b < 4; ++b) {
            int s = s0 + b;
            bf16x8 pk;
#pragma unroll
            for (int a = 0; a < 8; ++a)
                pk[a] = (short)f2bf(fmaxf(accL[a][b] + rb1[a], 0.f));
            *(bf16x8*)&h1bf[((s << 7) + o0) ^ ((s & 7) << 3)] = pk;
        }
    }
    __syncthreads();

    const int wv = t >> 6, lane = t & 63, lr = lane & 15, lg = lane >> 4;

    {
        f32x4 c2[2][4];
#pragma unroll
        for (int m = 0; m < 2; ++m)
#pragma unroll
            for (int n = 0; n < 4; ++n) c2[m][n] = (f32x4){0.f, 0.f, 0.f, 0.f};
#pragma unroll
        for (int kt = 0; kt < 4; ++kt) {
            bf16x8 af[2], bfr[4];
#pragma unroll
            for (int m = 0; m < 2; ++m)
                af[m] = *(const bf16x8*)&w2bf[(32 * wv + 16 * m + lr) * 128 + kt * 32 + lg * 8];
#pragma unroll
            for (int n = 0; n < 4; ++n) {
                int s = 16 * n + lr;
                bfr[n] = *(const bf16x8*)&h1bf[((s << 7) + kt * 32 + lg * 8) ^ ((s & 7) << 3)];
            }
#pragma unroll
            for (int m = 0; m < 2; ++m)
#pragma unroll
                for (int n = 0; n < 4; ++n)
                    c2[m][n] = MFMA16(af[m], bfr[n], c2[m][n]);
        }
        float rb[2][4];
#pragma unroll
        for (int m = 0; m < 2; ++m)
#pragma unroll
            for (int r = 0; r < 4; ++r) rb[m][r] = b2[32 * wv + 16 * m + lg * 4 + r];
#pragma unroll
        for (int m = 0; m < 2; ++m)
#pragma unroll
            for (int n = 0; n < 4; ++n) {
                int s = 16 * n + lr;
                s16x4 pk;
#pragma unroll
                for (int r = 0; r < 4; ++r)
                    pk[r] = (short)f2bf(fmaxf(c2[m][n][r] + rb[m][r], 0.f));
                int ob2 = 32 * wv + 16 * m + lg * 4;
                *(s16x4*)&h2bf[((s << 7) + ob2) ^ ((s & 7) << 3)] = pk;
            }
    }
    __syncthreads();

    {
        f32x4 c3[6];
#pragma unroll
        for (int m = 0; m < 6; ++m) c3[m] = (f32x4){0.f, 0.f, 0.f, 0.f};
        const int sB = 16 * wv + lr;
#pragma unroll
        for (int kt = 0; kt < 4; ++kt) {
            bf16x8 bfr = *(const bf16x8*)&h2bf[((sB << 7) + kt * 32 + lg * 8) ^ ((sB & 7) << 3)];
#pragma unroll
            for (int mt = 0; mt < 6; ++mt) {
                bf16x8 af = *(const bf16x8*)&w3bf[(16 * mt + lr) * 128 + kt * 32 + lg * 8];
                c3[mt] = MFMA16(af, bfr, c3[mt]);
            }
        }
#pragma unroll
        for (int mt = 0; mt < 6; ++mt)
#pragma unroll
            for (int r = 0; r < 4; ++r) {
                int o = 16 * mt + lg * 4 + r;
                if (o < 90) Rl[sB * 90 + o] = c3[mt][r] + b3[o];
            }
    }
    __syncthreads();

    {
        const float4* R4v = (const float4*)Rl;
        float4* G4 = (float4*)(recon_out + (size_t)row0 * 90);
#pragma unroll
        for (int it = 0; it < 6; ++it) {
            int i4 = it * 256 + t;
            if (i4 < 1440) G4[i4] = R4v[i4];
        }
    }
}

// ---------------------------------------------------------------------------
__global__ void k_loss(const float* __restrict__ acc, float* __restrict__ out) {
    out[0] = acc[0] * (1.0f / ((float)NSAMP * (float)DLAT));
}

extern "C" void kernel_launch(void* const* d_in, const int* in_sizes, int n_in,
                              void* d_out, int out_size, void* d_ws, size_t ws_size,
                              hipStream_t stream) {
    const float* state  = (const float*)d_in[0];
    const float* enc_w1 = (const float*)d_in[1];
    const float* enc_b1 = (const float*)d_in[2];
    const float* enc_w2 = (const float*)d_in[3];
    const float* enc_b2 = (const float*)d_in[4];
    const float* enc_w3 = (const float*)d_in[5];
    const float* enc_b3 = (const float*)d_in[6];
    const float* dec_w1 = (const float*)d_in[7];
    const float* dec_b1 = (const float*)d_in[8];
    const float* dec_w2 = (const float*)d_in[9];
    const float* dec_b2 = (const float*)d_in[10];
    const float* dec_w3 = (const float*)d_in[11];
    const float* dec_b3 = (const float*)d_in[12];
    const float* cb     = (const float*)d_in[13];

    float* out = (float*)d_out;
    float* P   = out;
    float* M   = out + 16384;
    ushort_t* Mhi = (ushort_t*)(out + 32768);
    ushort_t* Mlo = (ushort_t*)(out + 40960);
    float* t0  = out + 49152;
    float* v   = out + 49280;
    float* csc = out + 49408;
    ushort_t* w2ehi = (ushort_t*)(out + 49664);
    ushort_t* w2elo = (ushort_t*)(out + 57856);
    ushort_t* w1ehi = (ushort_t*)(out + 66048);
    ushort_t* w1elo = (ushort_t*)(out + 74240);
    float* ws = (float*)d_ws;
    float* loss_acc = ws;
    float* cbW = ws + 256;
    ushort_t* Qbf  = (ushort_t*)(ws + 16640);
    ushort_t* w2bf = (ushort_t*)(ws + 24832);
    ushort_t* w3bf = (ushort_t*)(ws + 33024);

    hipMemsetAsync(d_ws, 0, 16, stream);
    k_prep<<<576, 256, 0, stream>>>(cb, enc_w3, enc_b3, dec_w1, dec_w2, dec_w3,
                                    enc_w2, enc_w1,
                                    P, M, t0, v, csc, cbW, Qbf, w2bf, w3bf,
                                    Mhi, Mlo, w2ehi, w2elo, w1ehi, w1elo);
    k_encvq<<<NSAMP / 64, 256, 0, stream>>>(state, enc_w1, enc_b1, enc_w2, enc_b2,
                                            w1ehi, w1elo, w2ehi, w2elo,
                                            M, Qbf, Mhi, Mlo, t0, v, csc, P,
                                            out + OFF_CODE, loss_acc);
    k_dec<<<NSAMP / 64, 256, 0, stream>>>(out + OFF_CODE, cb, cbW,
                                          dec_b1, w2bf, dec_b2, w3bf, dec_b3,
                                          out, out + OFF_RECON);
    k_loss<<<1, 1, 0, stream>>>(loss_acc, out + OFF_LOSS);
}

// Round 16
// 288.462 us; speedup vs baseline: 1.2212x; 1.2212x over previous
//
#include <hip/hip_runtime.h>
#include <hip/hip_bf16.h>

#define NSAMP 131072
#define TA    90
#define HID   128
#define DLAT  512

// d_out layout (float elements): quant[N*512], code[N*4], recon[N*90], loss[1]
#define OFF_CODE  67108864ll
#define OFF_RECON (67108864ll + 524288ll)
#define OFF_LOSS  (67108864ll + 524288ll + 11796480ll)

// encvq arena (floats): splits/zdot[0..8704) | PZ[8704..8960)
#define PZF    8704
#define SHF    8960
#define MSKF   8256
#define H2AF   8272
#define H2BF   8400
#define TAU    0.08f

typedef __attribute__((ext_vector_type(8))) short bf16x8;
typedef __attribute__((ext_vector_type(4))) short s16x4;
typedef __attribute__((ext_vector_type(4))) float f32x4;
typedef unsigned short ushort_t;
#define MFMA16(a, b, c) __builtin_amdgcn_mfma_f32_16x16x32_bf16(a, b, c, 0, 0, 0)

__device__ __forceinline__ ushort_t f2bf(float f) {
    unsigned u = __float_as_uint(f);
    u = (u + 0x7FFF + ((u >> 16) & 1)) >> 16;     // RNE
    return (ushort_t)u;
}
__device__ __forceinline__ float bf2f(ushort_t u) {
    return __uint_as_float(((unsigned)u) << 16);
}
__device__ __forceinline__ void nt_store4(float* p, float x0, float x1,
                                          float x2, float x3) {
    f32x4 v = {x0, x1, x2, x3};
    __builtin_nontemporal_store(v, (f32x4*)p);
}

__device__ __forceinline__ float dot512(const float* __restrict__ a,
                                        const float* __restrict__ b) {
    float s = 0.f;
    for (int i = 0; i < 128; ++i) {
        float4 x = ((const float4*)a)[i], y = ((const float4*)b)[i];
        s += x.x * y.x + x.y * y.y + x.z * y.z + x.w * y.w;
    }
    return s;
}

// ---------------------------------------------------------------------------
// K0: precompute tables (R14 verbatim; destinations are caller-chosen).
// ---------------------------------------------------------------------------
__global__ void k_prep(const float* __restrict__ cb, const float* __restrict__ w3,
                       const float* __restrict__ b3, const float* __restrict__ w1d,
                       const float* __restrict__ w2d, const float* __restrict__ w3d,
                       const float* __restrict__ w2e, const float* __restrict__ w1e,
                       float* __restrict__ P, float* __restrict__ M,
                       float* __restrict__ t0, float* __restrict__ v,
                       float* __restrict__ csc, float* __restrict__ cbW,
                       ushort_t* __restrict__ Qbf, ushort_t* __restrict__ w2bf,
                       ushort_t* __restrict__ w3bf,
                       ushort_t* __restrict__ Mhibf, ushort_t* __restrict__ Mlobf,
                       ushort_t* __restrict__ w2ehi, ushort_t* __restrict__ w2elo,
                       ushort_t* __restrict__ w1ehi, ushort_t* __restrict__ w1elo) {
    int tbl = blockIdx.x >> 6;
    int gid = (blockIdx.x & 63) * 256 + threadIdx.x;   // 0..16383
    int i = gid >> 7, j = gid & 127;
    if (tbl == 0) {
        P[gid] = dot512(cb + (size_t)i * 512, cb + (size_t)j * 512);
        if (gid < 128) t0[gid] = dot512(cb + (size_t)gid * 512, b3);
        if (gid == 0) csc[0] = dot512(b3, b3);
    } else if (tbl == 1) {
        M[gid] = dot512(w3 + (size_t)i * 512, cb + (size_t)j * 512);
    } else if (tbl == 2) {
        Qbf[gid] = f2bf(dot512(w3 + (size_t)i * 512, w3 + (size_t)j * 512));
        if (gid < 128) v[gid] = dot512(w3 + (size_t)gid * 512, b3);
    } else if (tbl == 3) {
        float s = 0.f;
        for (int d = 0; d < 512; ++d) s = fmaf(cb[(size_t)i * 512 + d], w1d[d * 128 + j], s);
        cbW[gid] = s;
    } else if (tbl == 4) {
        w2bf[gid] = f2bf(w2d[j * 128 + i]);            // [o][j] = w2d[j][o]
    } else if (tbl == 5) {
        if (gid < 96 * 128)
            w3bf[gid] = (i < 90) ? f2bf(w3d[j * TA + i]) : (ushort_t)0;
    } else if (tbl == 6) {
        float d = dot512(w3 + (size_t)j * 512, cb + (size_t)i * 512);
        ushort_t hi = f2bf(d);
        Mhibf[gid] = hi;
        Mlobf[gid] = f2bf(d - bf2f(hi));
    } else if (tbl == 7) {
        float d = w2e[j * 128 + i];
        ushort_t hi = f2bf(d);
        w2ehi[gid] = hi;
        w2elo[gid] = f2bf(d - bf2f(hi));
    } else {
        float d = (j < 90) ? w1e[(size_t)j * 128 + i] : 0.f;
        ushort_t hi = f2bf(d);
        w1ehi[gid] = hi;
        w1elo[gid] = f2bf(d - bf2f(hi));
    }
}

// ===========================================================================
// Shared device bodies (verbatim R14 logic), inlined into both paths.
// ===========================================================================
__device__ __forceinline__ void enc_body(
        const float* __restrict__ X,
        const float* __restrict__ ew1, const float* __restrict__ eb1,
        const float* __restrict__ ew2, const float* __restrict__ eb2,
        const ushort_t* __restrict__ w1ehi, const ushort_t* __restrict__ w1elo,
        const ushort_t* __restrict__ w2ehi, const ushort_t* __restrict__ w2elo,
        const float* __restrict__ Mt, const ushort_t* __restrict__ Qbf,
        const ushort_t* __restrict__ Mhi, const ushort_t* __restrict__ Mlo,
        const float* __restrict__ t0g, const float* __restrict__ vg,
        const float* __restrict__ cg, const float* __restrict__ Pg,
        float* __restrict__ codes_out, float* __restrict__ loss_acc,
        float* SH, int t, int row0, int (&cs)[4]) {
    ushort_t* sphi = (ushort_t*)SH;
    ushort_t* splo = (ushort_t*)(SH + 4096);
    const int wv = t >> 6, lane = t & 63, lr = lane & 15, lg = lane >> 4;

    // stage X as bf16 hi/lo splits, swizzled [s][j<96]
    for (int it = 0; it < 24; ++it) {
        int idx = it * 256 + t;
        int s = idx / 96, j = idx - 96 * s;
        float xv = (j < 90) ? X[(size_t)(row0 + s) * TA + j] : 0.f;
        ushort_t hi = f2bf(xv);
        int adr = ((s << 7) + j) ^ ((s & 7) << 3);
        sphi[adr] = hi;
        splo[adr] = f2bf(xv - bf2f(hi));
    }
    __syncthreads();

    // L1 split-bf16 MFMA (K=96)
    {
        f32x4 c1[2][4];
#pragma unroll
        for (int m = 0; m < 2; ++m)
#pragma unroll
            for (int n = 0; n < 4; ++n) c1[m][n] = (f32x4){0.f, 0.f, 0.f, 0.f};
#pragma unroll
        for (int kt = 0; kt < 3; ++kt) {
            bf16x8 ah[2], al[2], bhi[4], blo[4];
#pragma unroll
            for (int m = 0; m < 2; ++m) {
                int arow = (32 * wv + 16 * m + lr) * 128 + kt * 32 + lg * 8;
                ah[m] = *(const bf16x8*)&w1ehi[arow];
                al[m] = *(const bf16x8*)&w1elo[arow];
            }
#pragma unroll
            for (int n = 0; n < 4; ++n) {
                int s = 16 * n + lr;
                int adr = ((s << 7) + kt * 32 + lg * 8) ^ ((s & 7) << 3);
                bhi[n] = *(const bf16x8*)&sphi[adr];
                blo[n] = *(const bf16x8*)&splo[adr];
            }
#pragma unroll
            for (int m = 0; m < 2; ++m)
#pragma unroll
                for (int n = 0; n < 4; ++n) {
                    c1[m][n] = MFMA16(ah[m], bhi[n], c1[m][n]);
                    c1[m][n] = MFMA16(ah[m], blo[n], c1[m][n]);
                    c1[m][n] = MFMA16(al[m], bhi[n], c1[m][n]);
                }
        }
        __syncthreads();
        float rbf[2][4];
#pragma unroll
        for (int m = 0; m < 2; ++m)
#pragma unroll
            for (int r = 0; r < 4; ++r) rbf[m][r] = eb1[32 * wv + 16 * m + lg * 4 + r];
#pragma unroll
        for (int m = 0; m < 2; ++m)
#pragma unroll
            for (int n = 0; n < 4; ++n) {
                int s = 16 * n + lr;
                s16x4 ph, pl;
#pragma unroll
                for (int r = 0; r < 4; ++r) {
                    float hv = fmaxf(c1[m][n][r] + rbf[m][r], 0.f);
                    ushort_t hi = f2bf(hv);
                    ph[r] = (short)hi;
                    pl[r] = (short)f2bf(hv - bf2f(hi));
                }
                int ob2 = 32 * wv + 16 * m + lg * 4;
                int adr = ((s << 7) + ob2) ^ ((s & 7) << 3);
                *(s16x4*)&sphi[adr] = ph;
                *(s16x4*)&splo[adr] = pl;
            }
    }
    __syncthreads();

    // L2 split-bf16 MFMA
    {
        f32x4 c2[2][4];
#pragma unroll
        for (int m = 0; m < 2; ++m)
#pragma unroll
            for (int n = 0; n < 4; ++n) c2[m][n] = (f32x4){0.f, 0.f, 0.f, 0.f};
#pragma unroll
        for (int kt = 0; kt < 4; ++kt) {
            bf16x8 ah[2], al[2], bhi[4], blo[4];
#pragma unroll
            for (int m = 0; m < 2; ++m) {
                int arow = (32 * wv + 16 * m + lr) * 128 + kt * 32 + lg * 8;
                ah[m] = *(const bf16x8*)&w2ehi[arow];
                al[m] = *(const bf16x8*)&w2elo[arow];
            }
#pragma unroll
            for (int n = 0; n < 4; ++n) {
                int s = 16 * n + lr;
                int adr = ((s << 7) + kt * 32 + lg * 8) ^ ((s & 7) << 3);
                bhi[n] = *(const bf16x8*)&sphi[adr];
                blo[n] = *(const bf16x8*)&splo[adr];
            }
#pragma unroll
            for (int m = 0; m < 2; ++m)
#pragma unroll
                for (int n = 0; n < 4; ++n) {
                    c2[m][n] = MFMA16(ah[m], bhi[n], c2[m][n]);
                    c2[m][n] = MFMA16(ah[m], blo[n], c2[m][n]);
                    c2[m][n] = MFMA16(al[m], bhi[n], c2[m][n]);
                }
        }
        __syncthreads();
        float rbf[2][4];
#pragma unroll
        for (int m = 0; m < 2; ++m)
#pragma unroll
            for (int r = 0; r < 4; ++r) rbf[m][r] = eb2[32 * wv + 16 * m + lg * 4 + r];
#pragma unroll
        for (int m = 0; m < 2; ++m)
#pragma unroll
            for (int n = 0; n < 4; ++n) {
                int s = 16 * n + lr;
                s16x4 ph, pl;
#pragma unroll
                for (int r = 0; r < 4; ++r) {
                    float hv = fmaxf(c2[m][n][r] + rbf[m][r], 0.f);
                    ushort_t hi = f2bf(hv);
                    ph[r] = (short)hi;
                    pl[r] = (short)f2bf(hv - bf2f(hi));
                }
                int ob2 = 32 * wv + 16 * m + lg * 4;
                int adr = ((s << 7) + ob2) ^ ((s & 7) << 3);
                *(s16x4*)&sphi[adr] = ph;
                *(s16x4*)&splo[adr] = pl;
            }
    }
    __syncthreads();

    // scoring + Q-loss MFMA phase
    f32x4 sc[2][4];
    {
        f32x4 qc[2][4];
#pragma unroll
        for (int m = 0; m < 2; ++m)
#pragma unroll
            for (int n = 0; n < 4; ++n) {
                qc[m][n] = (f32x4){0.f, 0.f, 0.f, 0.f};
                sc[m][n] = (f32x4){0.f, 0.f, 0.f, 0.f};
            }
#pragma unroll
        for (int kt = 0; kt < 4; ++kt) {
            bf16x8 aq[2], amh[2], aml[2], bhi[4], blo[4];
#pragma unroll
            for (int m = 0; m < 2; ++m) {
                int arow = (32 * wv + 16 * m + lr) * 128 + kt * 32 + lg * 8;
                aq[m]  = *(const bf16x8*)&Qbf[arow];
                amh[m] = *(const bf16x8*)&Mhi[arow];
                aml[m] = *(const bf16x8*)&Mlo[arow];
            }
#pragma unroll
            for (int n = 0; n < 4; ++n) {
                int s = 16 * n + lr;
                int adr = ((s << 7) + kt * 32 + lg * 8) ^ ((s & 7) << 3);
                bhi[n] = *(const bf16x8*)&sphi[adr];
                blo[n] = *(const bf16x8*)&splo[adr];
            }
#pragma unroll
            for (int m = 0; m < 2; ++m)
#pragma unroll
                for (int n = 0; n < 4; ++n) {
                    qc[m][n] = MFMA16(aq[m], bhi[n], qc[m][n]);
                    sc[m][n] = MFMA16(amh[m], bhi[n], sc[m][n]);
                    sc[m][n] = MFMA16(amh[m], blo[n], sc[m][n]);
                    sc[m][n] = MFMA16(aml[m], bhi[n], sc[m][n]);
                }
        }
        float v2[2][4];
#pragma unroll
        for (int m = 0; m < 2; ++m)
#pragma unroll
            for (int r = 0; r < 4; ++r) v2[m][r] = 2.f * vg[32 * wv + 16 * m + lg * 4 + r];
#pragma unroll
        for (int n = 0; n < 4; ++n) {
            int s = 16 * n + lr;
            float p = 0.f;
#pragma unroll
            for (int m = 0; m < 2; ++m)
#pragma unroll
                for (int r = 0; r < 4; ++r) {
                    int o = 32 * wv + 16 * m + lg * 4 + r;
                    int adr = ((s << 7) + o) ^ ((s & 7) << 3);
                    float hv = bf2f(sphi[adr]) + bf2f(splo[adr]);
                    p = fmaf(qc[m][n][r] + v2[m][r], hv, p);
                }
            p += __shfl_xor(p, 16);
            p += __shfl_xor(p, 32);
            if (lg == 0) SH[PZF + wv * 64 + s] = p;
        }
    }
    __syncthreads();

    // dump zdot
#pragma unroll
    for (int m = 0; m < 2; ++m)
#pragma unroll
        for (int n = 0; n < 4; ++n) {
            int s = 16 * n + lr;
#pragma unroll
            for (int r = 0; r < 4; ++r) {
                int o = 32 * wv + 16 * m + lg * 4 + r;
                SH[s * 129 + o] = sc[m][n][r] + t0g[o];
            }
        }
    __syncthreads();

    // argmin with margin tracking; wave-0 ballot -> mask
    if (t < 64) {
        float marg = 3.4e38f;
#pragma unroll
        for (int g = 0; g < 4; ++g) {
            float best = 3.4e38f, best2 = 3.4e38f; int bi = g * 32;
#pragma unroll
            for (int k = 0; k < 32; ++k) {
                int c = g * 32 + k;
                float zd = SH[t * 129 + c];
                float nr = Pg[c * 128 + c];
                float a2 = 0.f;
#pragma unroll
                for (int gp = 0; gp < g; ++gp) a2 += Pg[cs[gp] * 128 + c];
                float dist = nr - 2.f * (zd - a2);
                if (dist < best) { best2 = best; best = dist; bi = c; }
                else if (dist < best2) { best2 = dist; }
            }
            cs[g] = bi;
            float m2 = best2 - best;
            marg = (m2 < marg) ? m2 : marg;
        }
        unsigned long long mk = __ballot(marg < TAU);
        if (t == 0) *(unsigned long long*)&SH[MSKF] = mk;
    }
    __syncthreads();

    const unsigned long long mask = *(const unsigned long long*)&SH[MSKF];

    // exact full-chain fallback (pair-parallel)
    {
        unsigned long long mk = mask;
        while (mk) {
            int nA = (int)__ffsll((long long)mk) - 1; mk &= mk - 1;
            int nB = -1;
            if (mk) { nB = (int)__ffsll((long long)mk) - 1; mk &= mk - 1; }
            int grp = t >> 7, tt = t & 127;
            int s2 = grp ? nB : nA;
            float hv1 = 0.f;
            if (s2 >= 0) {
                const float* xr = X + (size_t)(row0 + s2) * TA;
                for (int j = 0; j < 90; ++j)
                    hv1 = fmaf(xr[j], ew1[j * 128 + tt], hv1);
                hv1 = fmaxf(hv1 + eb1[tt], 0.f);
                SH[(grp ? H2BF : H2AF) + tt] = hv1;
            }
            __syncthreads();
            float hv2 = 0.f;
            if (s2 >= 0) {
                const float* h1c = &SH[grp ? H2BF : H2AF];
                for (int j = 0; j < 128; ++j)
                    hv2 = fmaf(h1c[j], ew2[(size_t)j * 128 + tt], hv2);
                hv2 = fmaxf(hv2 + eb2[tt], 0.f);
            }
            __syncthreads();
            if (s2 >= 0) SH[(grp ? H2BF : H2AF) + tt] = hv2;
            __syncthreads();
            if (s2 >= 0) {
                const float* h2c = &SH[grp ? H2BF : H2AF];
                float a = 0.f;
                for (int j = 0; j < 128; ++j)
                    a = fmaf(h2c[j], Mt[(size_t)j * 128 + tt], a);
                SH[s2 * 129 + tt] = a + t0g[tt];
            }
            __syncthreads();
        }
    }

    if (t < 64 && ((mask >> t) & 1ull)) {
#pragma unroll
        for (int g = 0; g < 4; ++g) {
            float best = 3.4e38f; int bi = g * 32;
#pragma unroll
            for (int k = 0; k < 32; ++k) {
                int c = g * 32 + k;
                float zd = SH[t * 129 + c];
                float nr = Pg[c * 128 + c];
                float a2 = 0.f;
#pragma unroll
                for (int gp = 0; gp < g; ++gp) a2 += Pg[cs[gp] * 128 + c];
                float dist = nr - 2.f * (zd - a2);
                if (dist < best) { best = dist; bi = c; }
            }
            cs[g] = bi;
        }
    }

    // loss + codes
    if (t < 64) {
        float znorm = cg[0] + SH[PZF + t] + SH[PZF + 64 + t]
                    + SH[PZF + 128 + t] + SH[PZF + 192 + t];
        float S1 = 0.f, Sp = 0.f, msum = 0.f;
#pragma unroll
        for (int g = 0; g < 4; ++g) {
            int c = cs[g];
            float zd = SH[t * 129 + c];
            float nr = Pg[c * 128 + c];
            float a2 = 0.f;
#pragma unroll
            for (int gp = 0; gp < g; ++gp) a2 += Pg[cs[gp] * 128 + c];
            S1 += zd;
            Sp += nr + 2.f * a2;
            msum += (znorm - 2.f * S1 + Sp);
            codes_out[(size_t)(row0 + t) * 4 + g] = (float)(cs[g] - g * 32);
        }
#pragma unroll
        for (int off = 32; off; off >>= 1) msum += __shfl_down(msum, off);
        if (t == 0) atomicAdd(&loss_acc[0], msum);
    }
}

__device__ __forceinline__ void dec_body(
        const float* __restrict__ cb, const float* __restrict__ cbW,
        const float* __restrict__ b1, const ushort_t* __restrict__ w2bf,
        const float* __restrict__ b2, const ushort_t* __restrict__ w3bf,
        const float* __restrict__ b3,
        float* __restrict__ quant_out, float* __restrict__ recon_out,
        unsigned char* SHB, int t, int row0) {
    int* cods = (int*)SHB;
    ushort_t* h2bf = (ushort_t*)SHB;
    ushort_t* h1bf = (ushort_t*)(SHB + 16384);
    float* Rl = (float*)(SHB + 16384);
    const int st = t & 15, ct = t >> 4;
    const int s0 = st * 4, o0 = ct * 8;

    float rb1[8];
#pragma unroll
    for (int i = 0; i < 8; ++i) rb1[i] = b1[o0 + i];

    for (int i = 0; i < 32; ++i) {
        int idx4 = i * 256 + t;
        int s = idx4 >> 7, d4 = (idx4 & 127) * 4;
        const int* cp = &cods[s * 4];
        float4 a = *(const float4*)&cb[(size_t)cp[0] * 512 + d4];
        float4 b = *(const float4*)&cb[(size_t)cp[1] * 512 + d4];
        float4 c = *(const float4*)&cb[(size_t)cp[2] * 512 + d4];
        float4 d = *(const float4*)&cb[(size_t)cp[3] * 512 + d4];
        nt_store4(&quant_out[(size_t)(row0 + s) * 512 + d4],
                  a.x + b.x + c.x + d.x, a.y + b.y + c.y + d.y,
                  a.z + b.z + c.z + d.z, a.w + b.w + c.w + d.w);
    }

    {
        float accL[8][4];
#pragma unroll
        for (int b = 0; b < 4; ++b) {
            const int* cp = &cods[(s0 + b) * 4];
            float u[8] = {0, 0, 0, 0, 0, 0, 0, 0};
#pragma unroll
            for (int g = 0; g < 4; ++g) {
                const float* r = &cbW[(size_t)cp[g] * 128 + o0];
                float4 x0 = *(const float4*)r, x1 = *(const float4*)(r + 4);
                u[0] += x0.x; u[1] += x0.y; u[2] += x0.z; u[3] += x0.w;
                u[4] += x1.x; u[5] += x1.y; u[6] += x1.z; u[7] += x1.w;
            }
#pragma unroll
            for (int a = 0; a < 8; ++a) accL[a][b] = u[a];
        }
#pragma unroll
        for (int b = 0; b < 4; ++b) {
            int s = s0 + b;
            bf16x8 pk;
#pragma unroll
            for (int a = 0; a < 8; ++a)
                pk[a] = (short)f2bf(fmaxf(accL[a][b] + rb1[a], 0.f));
            *(bf16x8*)&h1bf[((s << 7) + o0) ^ ((s & 7) << 3)] = pk;
        }
    }
    __syncthreads();

    const int wv = t >> 6, lane = t & 63, lr = lane & 15, lg = lane >> 4;

    {
        f32x4 c2[2][4];
#pragma unroll
        for (int m = 0; m < 2; ++m)
#pragma unroll
            for (int n = 0; n < 4; ++n) c2[m][n] = (f32x4){0.f, 0.f, 0.f, 0.f};
#pragma unroll
        for (int kt = 0; kt < 4; ++kt) {
            bf16x8 af[2], bfr[4];
#pragma unroll
            for (int m = 0; m < 2; ++m)
                af[m] = *(const bf16x8*)&w2bf[(32 * wv + 16 * m + lr) * 128 + kt * 32 + lg * 8];
#pragma unroll
            for (int n = 0; n < 4; ++n) {
                int s = 16 * n + lr;
                bfr[n] = *(const bf16x8*)&h1bf[((s << 7) + kt * 32 + lg * 8) ^ ((s & 7) << 3)];
            }
#pragma unroll
            for (int m = 0; m < 2; ++m)
#pragma unroll
                for (int n = 0; n < 4; ++n)
                    c2[m][n] = MFMA16(af[m], bfr[n], c2[m][n]);
        }
        float rb[2][4];
#pragma unroll
        for (int m = 0; m < 2; ++m)
#pragma unroll
            for (int r = 0; r < 4; ++r) rb[m][r] = b2[32 * wv + 16 * m + lg * 4 + r];
#pragma unroll
        for (int m = 0; m < 2; ++m)
#pragma unroll
            for (int n = 0; n < 4; ++n) {
                int s = 16 * n + lr;
                s16x4 pk;
#pragma unroll
                for (int r = 0; r < 4; ++r)
                    pk[r] = (short)f2bf(fmaxf(c2[m][n][r] + rb[m][r], 0.f));
                int ob2 = 32 * wv + 16 * m + lg * 4;
                *(s16x4*)&h2bf[((s << 7) + ob2) ^ ((s & 7) << 3)] = pk;
            }
    }
    __syncthreads();

    {
        f32x4 c3[6];
#pragma unroll
        for (int m = 0; m < 6; ++m) c3[m] = (f32x4){0.f, 0.f, 0.f, 0.f};
        const int sB = 16 * wv + lr;
#pragma unroll
        for (int kt = 0; kt < 4; ++kt) {
            bf16x8 bfr = *(const bf16x8*)&h2bf[((sB << 7) + kt * 32 + lg * 8) ^ ((sB & 7) << 3)];
#pragma unroll
            for (int mt = 0; mt < 6; ++mt) {
                bf16x8 af = *(const bf16x8*)&w3bf[(16 * mt + lr) * 128 + kt * 32 + lg * 8];
                c3[mt] = MFMA16(af, bfr, c3[mt]);
            }
        }
#pragma unroll
        for (int mt = 0; mt < 6; ++mt)
#pragma unroll
            for (int r = 0; r < 4; ++r) {
                int o = 16 * mt + lg * 4 + r;
                if (o < 90) Rl[sB * 90 + o] = c3[mt][r] + b3[o];
            }
    }
    __syncthreads();

    {
        const float4* R4v = (const float4*)Rl;
        float* G = recon_out + (size_t)row0 * 90;
#pragma unroll
        for (int it = 0; it < 6; ++it) {
            int i4 = it * 256 + t;
            if (i4 < 1440) {
                float4 vv = R4v[i4];
                nt_store4(&G[i4 * 4], vv.x, vv.y, vv.z, vv.w);
            }
        }
    }
}

// ===========================================================================
// FUSED kernel: encoder + argmin + quant/decoder in one launch.
// ===========================================================================
__launch_bounds__(256, 4)
__global__ void k_fused(const float* __restrict__ X,
                        const float* __restrict__ ew1, const float* __restrict__ eb1,
                        const float* __restrict__ ew2, const float* __restrict__ eb2,
                        const ushort_t* __restrict__ w1ehi, const ushort_t* __restrict__ w1elo,
                        const ushort_t* __restrict__ w2ehi, const ushort_t* __restrict__ w2elo,
                        const float* __restrict__ Mt, const ushort_t* __restrict__ Qbf,
                        const ushort_t* __restrict__ Mhi, const ushort_t* __restrict__ Mlo,
                        const float* __restrict__ t0g, const float* __restrict__ vg,
                        const float* __restrict__ cg, const float* __restrict__ Pg,
                        float* __restrict__ codes_out, float* __restrict__ loss_acc,
                        const float* __restrict__ cb, const float* __restrict__ cbW,
                        const float* __restrict__ db1, const ushort_t* __restrict__ w2bf,
                        const float* __restrict__ db2, const ushort_t* __restrict__ w3bf,
                        const float* __restrict__ db3,
                        float* __restrict__ quant_out, float* __restrict__ recon_out) {
    __shared__ __align__(16) unsigned char SHB[39424];
    float* SH = (float*)SHB;
    const int t = threadIdx.x;
    const int row0 = blockIdx.x * 64;

    int cs[4] = {0, 32, 64, 96};
    enc_body(X, ew1, eb1, ew2, eb2, w1ehi, w1elo, w2ehi, w2elo,
             Mt, Qbf, Mhi, Mlo, t0g, vg, cg, Pg, codes_out, loss_acc,
             SH, t, row0, cs);

    // broadcast cods to LDS (zdot reads all done inside enc_body)
    __syncthreads();
    if (t < 64) {
#pragma unroll
        for (int g = 0; g < 4; ++g) ((int*)SHB)[t * 4 + g] = cs[g];
    }
    __syncthreads();

    dec_body(cb, cbW, db1, w2bf, db2, w3bf, db3, quant_out, recon_out,
             SHB, t, row0);
}

// ===========================================================================
// Fallback path kernels (R14 structure)
// ===========================================================================
__launch_bounds__(256, 4)
__global__ void k_encvq(const float* __restrict__ X,
                        const float* __restrict__ w1, const float* __restrict__ b1,
                        const float* __restrict__ w2, const float* __restrict__ b2,
                        const ushort_t* __restrict__ w1ehi, const ushort_t* __restrict__ w1elo,
                        const ushort_t* __restrict__ w2ehi, const ushort_t* __restrict__ w2elo,
                        const float* __restrict__ Mt, const ushort_t* __restrict__ Qbf,
                        const ushort_t* __restrict__ Mhi, const ushort_t* __restrict__ Mlo,
                        const float* __restrict__ t0g, const float* __restrict__ vg,
                        const float* __restrict__ cg, const float* __restrict__ Pg,
                        float* __restrict__ codes_out, float* __restrict__ loss_acc) {
    __shared__ __align__(16) float SH[SHF];
    const int t = threadIdx.x;
    const int row0 = blockIdx.x * 64;
    int cs[4] = {0, 32, 64, 96};
    enc_body(X, w1, b1, w2, b2, w1ehi, w1elo, w2ehi, w2elo,
             Mt, Qbf, Mhi, Mlo, t0g, vg, cg, Pg, codes_out, loss_acc,
             SH, t, row0, cs);
}

__launch_bounds__(256, 4)
__global__ void k_dec(const float* __restrict__ codes_f, const float* __restrict__ cb,
                      const float* __restrict__ cbW, const float* __restrict__ b1,
                      const ushort_t* __restrict__ w2bf, const float* __restrict__ b2,
                      const ushort_t* __restrict__ w3bf, const float* __restrict__ b3,
                      float* __restrict__ quant_out, float* __restrict__ recon_out) {
    __shared__ __align__(16) unsigned char SHB[39424];
    const int t = threadIdx.x;
    const int row0 = blockIdx.x * 64;
    ((int*)SHB)[t] = ((t & 3) << 5) + (int)codes_f[(size_t)row0 * 4 + t];
    __syncthreads();
    dec_body(cb, cbW, b1, w2bf, b2, w3bf, b3, quant_out, recon_out,
             SHB, t, row0);
}

// ---------------------------------------------------------------------------
__global__ void k_loss(const float* __restrict__ acc, float* __restrict__ out) {
    out[0] = acc[0] * (1.0f / ((float)NSAMP * (float)DLAT));
}

extern "C" void kernel_launch(void* const* d_in, const int* in_sizes, int n_in,
                              void* d_out, int out_size, void* d_ws, size_t ws_size,
                              hipStream_t stream) {
    const float* state  = (const float*)d_in[0];
    const float* enc_w1 = (const float*)d_in[1];
    const float* enc_b1 = (const float*)d_in[2];
    const float* enc_w2 = (const float*)d_in[3];
    const float* enc_b2 = (const float*)d_in[4];
    const float* enc_w3 = (const float*)d_in[5];
    const float* enc_b3 = (const float*)d_in[6];
    const float* dec_w1 = (const float*)d_in[7];
    const float* dec_b1 = (const float*)d_in[8];
    const float* dec_w2 = (const float*)d_in[9];
    const float* dec_b2 = (const float*)d_in[10];
    const float* dec_w3 = (const float*)d_in[11];
    const float* dec_b3 = (const float*)d_in[12];
    const float* cb     = (const float*)d_in[13];

    float* out = (float*)d_out;
    float* ws = (float*)d_ws;
    float* loss_acc = ws;
    float* cbW = ws + 256;
    ushort_t* Qbf  = (ushort_t*)(ws + 16640);
    ushort_t* w2bf = (ushort_t*)(ws + 24832);
    ushort_t* w3bf = (ushort_t*)(ws + 33024);

    hipMemsetAsync(d_ws, 0, 16, stream);

    const bool big = (ws_size >= (size_t)121728 * 4);
    if (big) {
        float* M   = ws + 39424;
        float* P   = ws + 55808;
        ushort_t* Mhi = (ushort_t*)(ws + 72192);
        ushort_t* Mlo = (ushort_t*)(ws + 80384);
        float* t0  = ws + 88576;
        float* v   = ws + 88704;
        float* csc = ws + 88832;
        ushort_t* w2ehi = (ushort_t*)(ws + 88960);
        ushort_t* w2elo = (ushort_t*)(ws + 97152);
        ushort_t* w1ehi = (ushort_t*)(ws + 105344);
        ushort_t* w1elo = (ushort_t*)(ws + 113536);
        k_prep<<<576, 256, 0, stream>>>(cb, enc_w3, enc_b3, dec_w1, dec_w2, dec_w3,
                                        enc_w2, enc_w1,
                                        P, M, t0, v, csc, cbW, Qbf, w2bf, w3bf,
                                        Mhi, Mlo, w2ehi, w2elo, w1ehi, w1elo);
        k_fused<<<NSAMP / 64, 256, 0, stream>>>(state, enc_w1, enc_b1, enc_w2, enc_b2,
                                                w1ehi, w1elo, w2ehi, w2elo,
                                                M, Qbf, Mhi, Mlo, t0, v, csc, P,
                                                out + OFF_CODE, loss_acc,
                                                cb, cbW, dec_b1, w2bf, dec_b2, w3bf,
                                                dec_b3, out, out + OFF_RECON);
    } else {
        float* P   = out;
        float* M   = out + 16384;
        ushort_t* Mhi = (ushort_t*)(out + 32768);
        ushort_t* Mlo = (ushort_t*)(out + 40960);
        float* t0  = out + 49152;
        float* v   = out + 49280;
        float* csc = out + 49408;
        ushort_t* w2ehi = (ushort_t*)(out + 49664);
        ushort_t* w2elo = (ushort_t*)(out + 57856);
        ushort_t* w1ehi = (ushort_t*)(out + 66048);
        ushort_t* w1elo = (ushort_t*)(out + 74240);
        k_prep<<<576, 256, 0, stream>>>(cb, enc_w3, enc_b3, dec_w1, dec_w2, dec_w3,
                                        enc_w2, enc_w1,
                                        P, M, t0, v, csc, cbW, Qbf, w2bf, w3bf,
                                        Mhi, Mlo, w2ehi, w2elo, w1ehi, w1elo);
        k_encvq<<<NSAMP / 64, 256, 0, stream>>>(state, enc_w1, enc_b1, enc_w2, enc_b2,
                                                w1ehi, w1elo, w2ehi, w2elo,
                                                M, Qbf, Mhi, Mlo, t0, v, csc, P,
                                                out + OFF_CODE, loss_acc);
        k_dec<<<NSAMP / 64, 256, 0, stream>>>(out + OFF_CODE, cb, cbW,
                                              dec_b1, w2bf, dec_b2, w3bf, dec_b3,
                                              out, out + OFF_RECON);
    }
    k_loss<<<1, 1, 0, stream>>>(loss_acc, out + OFF_LOSS);
}